// Round 8
// baseline (4406.441 us; speedup 1.0000x reference)
//
#include <hip/hip_runtime.h>
#include <hip/hip_fp16.h>

// Many2OneRNN: B=64, S=4096, I=256, H=256, O=128
// Phase 1 (k_xp):  xp3[b][h][t] = x·Wax^T + Wax_b + Waa_b  (MFMA, f16, t-contig)
// Phase 2 (k_rnn): MFMA recurrence. 4 blocks x 16 chains, 512 thr (8 waves,
//   2/SIMD).  Per step: C'[h][chain] = Waa a^T via mfma_16x16x32_f16.
//   Wave w owns h-tiles {w*32, w*32+16}: Waa A-frags in 64 VGPRs (invariant).
//   a-tile [16 chains][256+8 pad] f16 double-buffered in LDS; B-frag = one
//   ds_read_b128 per kk (shared by both tiles).  C' rows are k-contiguous ->
//   tanh + pack -> 2 ds_write_b64.  One raw barrier/step (lgkmcnt only,
//   xp prefetch stays in flight).  VALU now only tanh+glue.
// Phase 3: folded into last k_rnn: out = sigmoid(Wya*a + Wya_b).

typedef _Float16 f16x8 __attribute__((ext_vector_type(8)));
typedef _Float16 f16x4 __attribute__((ext_vector_type(4)));
typedef float    f32x4 __attribute__((ext_vector_type(4)));

// ---------------------------------------------------------------------------
// Phase 1: xp GEMM.  grid = T_C blocks (64 t-rows each), 512 threads.
// Output layout xp3[b][h][t_local] (f16, t-contiguous), BOTH biases folded.
// ---------------------------------------------------------------------------
__global__ __launch_bounds__(512) void k_xp(
    const float* __restrict__ x, const float* __restrict__ Ww,
    const float* __restrict__ Wb, const float* __restrict__ Wab,
    _Float16* __restrict__ xp, int c, int T_C, int logT)
{
    __shared__ __align__(16) _Float16 As[64 * 264];  // pad 256->264 halves
    const int tid  = threadIdx.x;
    const int lane = tid & 63;
    const int wv   = tid >> 6;   // 0..7
    const int l15  = lane & 15;
    const int lk   = lane >> 4;  // 0..3
    const int n0   = wv * 32;

    // --- B fragments (Wax_w rows = N dim, K contiguous) in registers
    f16x8 bfr[2][8];
#pragma unroll
    for (int nt = 0; nt < 2; ++nt) {
        const float* wrow = Ww + (size_t)(n0 + nt * 16 + l15) * 256;
#pragma unroll
        for (int kt = 0; kt < 8; ++kt) {
            const float4* wp = (const float4*)(wrow + kt * 32 + lk * 8);
            float4 v0 = wp[0], v1 = wp[1];
            f16x8 f;
            f[0] = (_Float16)v0.x; f[1] = (_Float16)v0.y;
            f[2] = (_Float16)v0.z; f[3] = (_Float16)v0.w;
            f[4] = (_Float16)v1.x; f[5] = (_Float16)v1.y;
            f[6] = (_Float16)v1.z; f[7] = (_Float16)v1.w;
            bfr[nt][kt] = f;
        }
    }
    const float bias0 = Wb[n0 + l15]      + Wab[n0 + l15];
    const float bias1 = Wb[n0 + 16 + l15] + Wab[n0 + 16 + l15];

    // --- stage A tile (64 rows x 256 K) f32 -> f16 LDS
    {
        const int arow = tid >> 3;           // 0..63
        const int acol = (tid & 7) * 32;     // 0..224
        const int r    = blockIdx.x * 64 + arow;
        const int bb   = r >> logT;
        const int tl   = r & (T_C - 1);
        const float4* s4 = (const float4*)(x + ((size_t)(bb * 4096 + c * T_C + tl) << 8) + acol);
        _Float16* d = As + arow * 264 + acol;
#pragma unroll
        for (int q = 0; q < 4; ++q) {
            float4 v0 = s4[2 * q], v1 = s4[2 * q + 1];
            f16x8 p;
            p[0] = (_Float16)v0.x; p[1] = (_Float16)v0.y;
            p[2] = (_Float16)v0.z; p[3] = (_Float16)v0.w;
            p[4] = (_Float16)v1.x; p[5] = (_Float16)v1.y;
            p[6] = (_Float16)v1.z; p[7] = (_Float16)v1.w;
            *(f16x8*)(d + q * 8) = p;
        }
    }
    __syncthreads();

    f32x4 acc[4][2] = {};
#pragma unroll
    for (int kt = 0; kt < 8; ++kt) {
#pragma unroll
        for (int mt = 0; mt < 4; ++mt) {
            f16x8 af = *(const f16x8*)(As + (mt * 16 + l15) * 264 + kt * 32 + lk * 8);
            acc[mt][0] = __builtin_amdgcn_mfma_f32_16x16x32_f16(af, bfr[0][kt], acc[mt][0], 0, 0, 0);
            acc[mt][1] = __builtin_amdgcn_mfma_f32_16x16x32_f16(af, bfr[1][kt], acc[mt][1], 0, 0, 0);
        }
    }

    // --- store xp3[b][h][t]: pack 4 t-contiguous halves -> one 8B store
    const int base = blockIdx.x * 64;
#pragma unroll
    for (int mt = 0; mt < 4; ++mt) {
        const int rr  = base + mt * 16 + lk * 4;   // 4-aligned t-run, one b
        const int bb2 = rr >> logT;
        const int tt  = rr & (T_C - 1);
#pragma unroll
        for (int nt = 0; nt < 2; ++nt) {
            const int   h    = n0 + nt * 16 + l15;
            const float bias = (nt == 0) ? bias0 : bias1;
            f16x4 pk;
#pragma unroll
            for (int r2 = 0; r2 < 4; ++r2) pk[r2] = (_Float16)(acc[mt][nt][r2] + bias);
            *(f16x4*)(xp + ((size_t)(bb2 * 256 + h)) * T_C + tt) = pk;
        }
    }
}

// ---------------------------------------------------------------------------
// Phase 2: MFMA recurrence.  grid = 4 blocks (16 chains each), 512 threads.
// ---------------------------------------------------------------------------
__global__ __launch_bounds__(512)
__attribute__((amdgpu_waves_per_eu(2, 2)))
void k_rnn(
    const _Float16* __restrict__ xp, const float* __restrict__ Waa,
    const float* __restrict__ Wya, const float* __restrict__ Wyb,
    float* __restrict__ out, unsigned short* __restrict__ a_state,
    int c, int T_C, int is_last)
{
    __shared__ __align__(16) _Float16 aL[2][16][264];  // [buf][chain][k + 8 pad]
    const int tid  = threadIdx.x;
    const int lane = tid & 63;
    const int wv   = tid >> 6;    // 0..7
    const int i15  = lane & 15;
    const int g    = lane >> 4;   // 0..3
    const int blk  = blockIdx.x;  // chains blk*16 .. +15
    const int chain_g = blk * 16 + i15;

    // --- A' weights: Waa rows for h-tiles wv*32 and wv*32+16 (64 VGPR)
    f16x8 wa0[8], wa1[8];
    {
        const float* w0 = Waa + (size_t)(wv * 32 + i15) * 256 + g * 8;
        const float* w1 = w0 + 16 * 256;
#pragma unroll
        for (int kk = 0; kk < 8; ++kk) {
            const float4* p0 = (const float4*)(w0 + kk * 32);
            float4 va = p0[0], vb = p0[1];
            f16x8 f;
            f[0] = (_Float16)va.x; f[1] = (_Float16)va.y;
            f[2] = (_Float16)va.z; f[3] = (_Float16)va.w;
            f[4] = (_Float16)vb.x; f[5] = (_Float16)vb.y;
            f[6] = (_Float16)vb.z; f[7] = (_Float16)vb.w;
            wa0[kk] = f;
            const float4* p1 = (const float4*)(w1 + kk * 32);
            float4 vc = p1[0], vd = p1[1];
            f16x8 f2;
            f2[0] = (_Float16)vc.x; f2[1] = (_Float16)vc.y;
            f2[2] = (_Float16)vc.z; f2[3] = (_Float16)vc.w;
            f2[4] = (_Float16)vd.x; f2[5] = (_Float16)vd.y;
            f2[6] = (_Float16)vd.z; f2[7] = (_Float16)vd.w;
            wa1[kk] = f2;
        }
    }

    // --- init a-tile buf0: 512 thr x 8 halves = 16x256
    {
        const int e = tid * 8, ch = e >> 8, k0 = e & 255;
        if (c == 0) {
            f16x8 z = {};
            *(f16x8*)&aL[0][ch][k0] = z;
        } else {
            *(uint4*)&aL[0][ch][k0] =
                *(const uint4*)&a_state[((size_t)(blk * 16 + ch) << 8) + k0];
        }
    }
    __syncthreads();

    // --- xp streams: 8 per lane (2 tiles x 4 rows), f16x4 per 4 steps,
    //     double-buffered so HBM latency hides under 4 steps of compute.
    const _Float16* xpb =
        xp + ((size_t)(chain_g * 256 + wv * 32 + g * 4)) * T_C;
    f16x4 xqA[2][4], xqB[2][4];

#define LOADX(X, T)                                                          \
    {                                                                        \
        _Pragma("unroll")                                                    \
        for (int t8 = 0; t8 < 2; ++t8) {                                     \
            _Pragma("unroll")                                                \
            for (int r = 0; r < 4; ++r)                                      \
                X[t8][r] = *(const f16x4*)(xpb + (size_t)(t8 * 16 + r) * T_C + (T)); \
        }                                                                    \
    }

#define STEP(P, X, J)                                                        \
    {                                                                        \
        const _Float16* arow_ = &aL[(P)][i15][g * 8];                        \
        f32x4 c0 = {0.f, 0.f, 0.f, 0.f}, c1 = {0.f, 0.f, 0.f, 0.f};          \
        _Pragma("unroll")                                                    \
        for (int kk = 0; kk < 8; ++kk) {                                     \
            f16x8 bf = *(const f16x8*)(arow_ + kk * 32);                     \
            c0 = __builtin_amdgcn_mfma_f32_16x16x32_f16(wa0[kk], bf, c0, 0, 0, 0); \
            c1 = __builtin_amdgcn_mfma_f32_16x16x32_f16(wa1[kk], bf, c1, 0, 0, 0); \
        }                                                                    \
        f16x4 o0, o1;                                                        \
        _Pragma("unroll")                                                    \
        for (int r = 0; r < 4; ++r) {                                        \
            float z0 = c0[r] + (float)X[0][r][(J)];                          \
            float e0 = __expf(2.f * z0);                                     \
            o0[r] = (_Float16)fmaf(-2.f, __builtin_amdgcn_rcpf(e0 + 1.f), 1.f); \
            float z1 = c1[r] + (float)X[1][r][(J)];                          \
            float e1 = __expf(2.f * z1);                                     \
            o1[r] = (_Float16)fmaf(-2.f, __builtin_amdgcn_rcpf(e1 + 1.f), 1.f); \
        }                                                                    \
        *(f16x4*)&aL[(P) ^ 1][i15][wv * 32 + g * 4]      = o0;               \
        *(f16x4*)&aL[(P) ^ 1][i15][wv * 32 + 16 + g * 4] = o1;               \
        asm volatile("s_waitcnt lgkmcnt(0)" ::: "memory");                   \
        __builtin_amdgcn_s_barrier();                                        \
        asm volatile("" ::: "memory");                                       \
    }

    LOADX(xqA, 0)
    for (int tb = 0; tb < T_C; tb += 8) {
        LOADX(xqB, tb + 4)                    // always in-range (T_C mult of 8)
        STEP(0, xqA, 0) STEP(1, xqA, 1) STEP(0, xqA, 2) STEP(1, xqA, 3)
        if (tb + 8 < T_C) LOADX(xqA, tb + 8)  // wave-uniform guard
        STEP(0, xqB, 0) STEP(1, xqB, 1) STEP(0, xqB, 2) STEP(1, xqB, 3)
    }
#undef STEP
#undef LOADX
    // T_C even -> final state is in aL[0]; last STEP's barrier makes it visible.

    // --- carry state for next chunk
    {
        const int e = tid * 8, ch = e >> 8, k0 = e & 255;
        *(uint4*)&a_state[((size_t)(blk * 16 + ch) << 8) + k0] =
            *(const uint4*)&aL[0][ch][k0];
    }

    // --- Phase 3: out = sigmoid(Wya * a_last + Wyb), last chunk only
    if (is_last) {
        const int ch = tid >> 5;          // 0..15
        const int og = (tid & 31) * 4;    // 0..124
        float s0 = Wyb[og], s1 = Wyb[og + 1], s2 = Wyb[og + 2], s3 = Wyb[og + 3];
        for (int kk = 0; kk < 32; ++kk) {
            f16x8 af = *(const f16x8*)&aL[0][ch][kk * 8];
            float a[8];
#pragma unroll
            for (int j = 0; j < 8; ++j) a[j] = (float)af[j];
#pragma unroll
            for (int q = 0; q < 4; ++q) {
                const float4* wp = (const float4*)(Wya + (size_t)(og + q) * 256 + kk * 8);
                float4 w0 = wp[0], w1 = wp[1];
                float t = w0.x * a[0] + w0.y * a[1] + w0.z * a[2] + w0.w * a[3]
                        + w1.x * a[4] + w1.y * a[5] + w1.z * a[6] + w1.w * a[7];
                if (q == 0) s0 += t; else if (q == 1) s1 += t;
                else if (q == 2) s2 += t; else s3 += t;
            }
        }
        float* op = out + (size_t)(blk * 16 + ch) * 128 + og;
        op[0] = __builtin_amdgcn_rcpf(1.f + __expf(-s0));
        op[1] = __builtin_amdgcn_rcpf(1.f + __expf(-s1));
        op[2] = __builtin_amdgcn_rcpf(1.f + __expf(-s2));
        op[3] = __builtin_amdgcn_rcpf(1.f + __expf(-s3));
    }
}

// ---------------------------------------------------------------------------
extern "C" void kernel_launch(void* const* d_in, const int* in_sizes, int n_in,
                              void* d_out, int out_size, void* d_ws, size_t ws_size,
                              hipStream_t stream)
{
    (void)in_sizes; (void)n_in; (void)out_size;
    const float* x    = (const float*)d_in[0];
    const float* Waxw = (const float*)d_in[1];
    const float* Waxb = (const float*)d_in[2];
    const float* Waaw = (const float*)d_in[3];
    const float* Waab = (const float*)d_in[4];
    const float* Wyaw = (const float*)d_in[5];
    const float* Wyab = (const float*)d_in[6];
    float* out = (float*)d_out;

    // Adaptive chunking over timesteps so the f16 xp chunk fits in d_ws.
    int T_C = 4096, logT = 12;
    while (T_C > 32 && (size_t)64 * T_C * 256 * 2 + 32768 > ws_size) { T_C >>= 1; --logT; }

    _Float16* xp = (_Float16*)d_ws;
    unsigned short* a_state =
        (unsigned short*)((char*)d_ws + (size_t)64 * T_C * 256 * 2);

    const int nc = 4096 / T_C;
    for (int ci = 0; ci < nc; ++ci) {
        k_xp<<<dim3(T_C), dim3(512), 0, stream>>>(x, Waxw, Waxb, Waab, xp, ci, T_C, logT);
        k_rnn<<<dim3(4), dim3(512), 0, stream>>>(xp, Waaw, Wyaw, Wyab,
                                                 out, a_state, ci, T_C, ci == nc - 1);
    }
}

// Round 9
// 1958.118 us; speedup vs baseline: 2.2503x; 2.2503x over previous
//
#include <hip/hip_runtime.h>
#include <hip/hip_fp16.h>

// Many2OneRNN: B=64, S=4096, I=256, H=256, O=128
// Fused heterogeneous kernel, chunked over time (T_C=1024, 4 chunks):
//   blocks 0..63   : recurrence for chunk c   (1 block/chain, 1024 thr)
//   blocks 64..    : xp GEMM for chunk c+1    (128 t-rows/block, MFMA f16)
// xp double-buffered in d_ws so launch i overlaps rnn(i-1) with xp(i).
// rnn per thread/step: 2 ds_read_b128 (broadcast), 32 fdot2,
//   5-DPP quad_perm+row_ror rotate-reduce, 5-op tanh, predicated ds_write.
// Phase 3 (out = sigmoid(Wya*a + Wya_b)) folded into the last rnn launch.

typedef _Float16 f16x8 __attribute__((ext_vector_type(8)));
typedef _Float16 f16x4 __attribute__((ext_vector_type(4)));
typedef _Float16 f16x2 __attribute__((ext_vector_type(2)));
typedef float    f32x4 __attribute__((ext_vector_type(4)));

#define FDOT2(a, b, c) __builtin_amdgcn_fdot2((a), (b), (c), false)

// row_ror:D within 16 lanes: dst lane i gets src lane (i-D)&15
template <int D>
__device__ __forceinline__ float rorf(float v) {
    return __builtin_bit_cast(float,
        __builtin_amdgcn_update_dpp(0, __builtin_bit_cast(int, v),
                                    0x120 + D, 0xF, 0xF, true));
}
// quad_perm rotate within 4 lanes: dst j gets src (j-D)&3
template <int D>
__device__ __forceinline__ float qrot(float v) {
    constexpr int ctrl = D == 1 ? 0x93 : (D == 2 ? 0x4E : 0x39);
    return __builtin_bit_cast(float,
        __builtin_amdgcn_update_dpp(0, __builtin_bit_cast(int, v),
                                    ctrl, 0xF, 0xF, true));
}

__global__ __launch_bounds__(1024) void k_fused(
    const float* __restrict__ x, const float* __restrict__ Ww,
    const float* __restrict__ Wb, const float* __restrict__ Waa,
    const float* __restrict__ Wab, const float* __restrict__ Wya,
    const float* __restrict__ Wyb, float* __restrict__ out,
    _Float16* __restrict__ xp0, _Float16* __restrict__ xp1,
    unsigned short* __restrict__ a_state,
    int c_rnn, int c_xp, int do_rnn, int do_xp, int is_last,
    int T_C, int logT)
{
    // LDS: xp path uses As (67.5 KB); rnn path uses aL/afin (2.5 KB).
    __shared__ __align__(16) _Float16 As[128 * 264];
    __shared__ __align__(16) _Float16 aL[2][16][24];
    __shared__ float afin[256];

    const int tid  = threadIdx.x;
    const int lane = tid & 63;

    if (blockIdx.x < 64) {
        // ================= RNN path =================
        if (!do_rnn) return;
        const _Float16* xp = (c_rnn & 1) ? xp1 : xp0;
        const int w     = tid >> 6;      // 0..15
        const int k     = lane & 15;     // K-slice [k*16, k*16+16)
        const int g     = lane >> 4;     // 0..3
        const int rbase = w * 16 + g * 4;
        const int myrow = rbase + (k & 3);
        const int b     = blockIdx.x;
        const bool wlane = (k & 12) == 0;

        // weights: slot i -> row rbase+((k+i)&3), K-contiguous f16x2
        f16x2 wr[4][8];
#pragma unroll
        for (int i = 0; i < 4; ++i) {
            const float4* wp = (const float4*)(Waa + (size_t)(rbase + ((k + i) & 3)) * 256 + k * 16);
#pragma unroll
            for (int q = 0; q < 4; ++q) {
                float4 v = wp[q];
                f16x2 t0; t0[0] = (_Float16)v.x; t0[1] = (_Float16)v.y;
                f16x2 t1; t1[0] = (_Float16)v.z; t1[1] = (_Float16)v.w;
                wr[i][2 * q]     = t0;
                wr[i][2 * q + 1] = t1;
            }
        }
        const float bias = Wab[myrow];

        if (tid < 256) {
            unsigned short v = 0;
            if (c_rnn != 0) v = a_state[b * 256 + tid];
            aL[0][tid >> 4][tid & 15] = __builtin_bit_cast(_Float16, v);
        }
        __syncthreads();

        const _Float16* xph = xp + ((size_t)(b * 256 + myrow)) * T_C;
        f16x8 xq = *(const f16x8*)(xph);
        float bx[8];
#pragma unroll
        for (int j = 0; j < 8; ++j) bx[j] = bias + (float)xq[j];

        const _Float16* rp0 = &aL[0][k][0];
        const _Float16* rp1 = &aL[1][k][0];
        _Float16* wq0 = &aL[1][w][g * 4 + k];  // wlane only (k<4)
        _Float16* wq1 = &aL[0][w][g * 4 + k];

#define RNN_STEP(J, FIN)                                                     \
    {                                                                        \
        const _Float16* rp = ((J) & 1) ? rp1 : rp0;                          \
        uint4 r0 = *(const uint4*)(rp);                                      \
        uint4 r1 = *(const uint4*)(rp + 8);                                  \
        f16x2 a2[8];                                                         \
        a2[0] = __builtin_bit_cast(f16x2, r0.x);                             \
        a2[1] = __builtin_bit_cast(f16x2, r0.y);                             \
        a2[2] = __builtin_bit_cast(f16x2, r0.z);                             \
        a2[3] = __builtin_bit_cast(f16x2, r0.w);                             \
        a2[4] = __builtin_bit_cast(f16x2, r1.x);                             \
        a2[5] = __builtin_bit_cast(f16x2, r1.y);                             \
        a2[6] = __builtin_bit_cast(f16x2, r1.z);                             \
        a2[7] = __builtin_bit_cast(f16x2, r1.w);                             \
        float s0 = 0.f, s1 = 0.f, s2 = 0.f, s3 = 0.f;                        \
        _Pragma("unroll")                                                    \
        for (int q = 0; q < 8; ++q) {                                        \
            s0 = FDOT2(wr[0][q], a2[q], s0);                                 \
            s1 = FDOT2(wr[1][q], a2[q], s1);                                 \
            s2 = FDOT2(wr[2][q], a2[q], s2);                                 \
            s3 = FDOT2(wr[3][q], a2[q], s3);                                 \
        }                                                                    \
        /* 5-DPP reduce: quad rotate-reduce then fold the 4 quads */         \
        float t = s0 + qrot<1>(s1);                                          \
        t += qrot<2>(s2);                                                    \
        t += qrot<3>(s3);                                                    \
        float u   = t + rorf<4>(t);                                          \
        float acc = u + rorf<8>(u);                                          \
        float z  = bx[(J)] + acc;                                            \
        float e2 = __expf(2.f * z);                                          \
        float a  = fmaf(-2.f, __builtin_amdgcn_rcpf(e2 + 1.f), 1.f);         \
        _Float16 ah = (_Float16)a;                                           \
        if (wlane) *(((J) & 1) ? wq1 : wq0) = ah;                            \
        if (FIN) {                                                           \
            afin[myrow] = a;                                                 \
            a_state[b * 256 + myrow] = __builtin_bit_cast(unsigned short, ah);\
        }                                                                    \
        asm volatile("s_waitcnt lgkmcnt(0)" ::: "memory");                   \
        __builtin_amdgcn_s_barrier();                                        \
        asm volatile("" ::: "memory");                                       \
    }

        for (int tb = 0; tb + 8 < T_C; tb += 8) {
            f16x8 xn = *(const f16x8*)(xph + tb + 8);
            RNN_STEP(0, false) RNN_STEP(1, false) RNN_STEP(2, false) RNN_STEP(3, false)
            RNN_STEP(4, false) RNN_STEP(5, false) RNN_STEP(6, false) RNN_STEP(7, false)
#pragma unroll
            for (int j = 0; j < 8; ++j) bx[j] = bias + (float)xn[j];
        }
        RNN_STEP(0, false) RNN_STEP(1, false) RNN_STEP(2, false) RNN_STEP(3, false)
        RNN_STEP(4, false) RNN_STEP(5, false) RNN_STEP(6, false) RNN_STEP(7, true)
#undef RNN_STEP

        if (is_last) {
            const int o  = tid >> 3;   // 0..127
            const int k8 = tid & 7;
            const float4* wp = (const float4*)(Wya + (size_t)o * 256 + k8 * 32);
            const float4* ap = (const float4*)(afin + k8 * 32);
            float s = 0.f;
#pragma unroll
            for (int i = 0; i < 8; ++i) {
                float4 wv4 = wp[i];
                float4 a4  = ap[i];
                s += wv4.x * a4.x + wv4.y * a4.y + wv4.z * a4.z + wv4.w * a4.w;
            }
            s += __shfl_xor(s, 1);
            s += __shfl_xor(s, 2);
            s += __shfl_xor(s, 4);
            if (k8 == 0)
                out[b * 128 + o] = __builtin_amdgcn_rcpf(1.f + __expf(-(s + Wyb[o])));
        }
    } else {
        // ================= XP path (chunk c_xp, 128 t-rows/block) =========
        if (!do_xp) return;
        _Float16* xp = (c_xp & 1) ? xp1 : xp0;
        const int bxp = blockIdx.x - 64;
        const int wv  = tid >> 6;    // 0..15
        const int l15 = lane & 15;
        const int lk  = lane >> 4;   // 0..3
        const int n0  = wv * 16;

        // B fragments: Wax_w rows n0+l15 (16 cols per wave), K-contiguous
        f16x8 bfr[8];
        {
            const float* wrow = Ww + (size_t)(n0 + l15) * 256;
#pragma unroll
            for (int kt = 0; kt < 8; ++kt) {
                const float4* wp = (const float4*)(wrow + kt * 32 + lk * 8);
                float4 v0 = wp[0], v1 = wp[1];
                f16x8 f;
                f[0] = (_Float16)v0.x; f[1] = (_Float16)v0.y;
                f[2] = (_Float16)v0.z; f[3] = (_Float16)v0.w;
                f[4] = (_Float16)v1.x; f[5] = (_Float16)v1.y;
                f[6] = (_Float16)v1.z; f[7] = (_Float16)v1.w;
                bfr[kt] = f;
            }
        }
        const float bias = Wb[n0 + l15];

        // stage A tile (128 rows x 256 K) f32 -> f16 LDS
        {
            const int arow = tid >> 3;           // 0..127
            const int acol = (tid & 7) * 32;     // 0..224
            const int r    = bxp * 128 + arow;
            const int bb   = r >> logT;
            const int tl   = r & (T_C - 1);
            const float4* s4 = (const float4*)(x + ((size_t)(bb * 4096 + c_xp * T_C + tl) << 8) + acol);
            _Float16* d = As + arow * 264 + acol;
#pragma unroll
            for (int q = 0; q < 4; ++q) {
                float4 v0 = s4[2 * q], v1 = s4[2 * q + 1];
                f16x8 p;
                p[0] = (_Float16)v0.x; p[1] = (_Float16)v0.y;
                p[2] = (_Float16)v0.z; p[3] = (_Float16)v0.w;
                p[4] = (_Float16)v1.x; p[5] = (_Float16)v1.y;
                p[6] = (_Float16)v1.z; p[7] = (_Float16)v1.w;
                *(f16x8*)(d + q * 8) = p;
            }
        }
        __syncthreads();

        f32x4 acc[8] = {};
#pragma unroll
        for (int kt = 0; kt < 8; ++kt) {
#pragma unroll
            for (int mt = 0; mt < 8; ++mt) {
                f16x8 af = *(const f16x8*)(As + (mt * 16 + l15) * 264 + kt * 32 + lk * 8);
                acc[mt] = __builtin_amdgcn_mfma_f32_16x16x32_f16(af, bfr[kt], acc[mt], 0, 0, 0);
            }
        }

        // store xp3[b][h][t]: 4 t-contiguous halves per 8B store
        const int base = bxp * 128;
#pragma unroll
        for (int mt = 0; mt < 8; ++mt) {
            const int rr  = base + mt * 16 + lk * 4;
            const int bb2 = rr >> logT;
            const int tt  = rr & (T_C - 1);
            f16x4 pk;
#pragma unroll
            for (int r2 = 0; r2 < 4; ++r2) pk[r2] = (_Float16)(acc[mt][r2] + bias);
            *(f16x4*)(xp + ((size_t)(bb2 * 256 + n0 + l15)) * T_C + tt) = pk;
        }
    }
}

// ---------------------------------------------------------------------------
extern "C" void kernel_launch(void* const* d_in, const int* in_sizes, int n_in,
                              void* d_out, int out_size, void* d_ws, size_t ws_size,
                              hipStream_t stream)
{
    (void)in_sizes; (void)n_in; (void)out_size;
    const float* x    = (const float*)d_in[0];
    const float* Waxw = (const float*)d_in[1];
    const float* Waxb = (const float*)d_in[2];
    const float* Waaw = (const float*)d_in[3];
    const float* Waab = (const float*)d_in[4];
    const float* Wyaw = (const float*)d_in[5];
    const float* Wyab = (const float*)d_in[6];
    float* out = (float*)d_out;

    // chunk size: T_C=1024 (4 chunks) for xp/rnn overlap; shrink to fit ws
    // (needs 2 xp chunk buffers + 32KB state).
    int T_C = 1024, logT = 10;
    while (T_C > 128 && (size_t)2 * 64 * T_C * 256 * 2 + 32768 > ws_size) { T_C >>= 1; --logT; }

    _Float16* xp0 = (_Float16*)d_ws;
    _Float16* xp1 = xp0 + (size_t)64 * T_C * 256;
    unsigned short* a_state = (unsigned short*)(xp1 + (size_t)64 * T_C * 256);

    const int nc  = 4096 / T_C;
    const int nxp = 64 * T_C / 128;   // xp blocks per chunk
    for (int i = 0; i <= nc; ++i) {
        // launch i: rnn on chunk i-1 (if any) overlapped with xp on chunk i
        k_fused<<<dim3(64 + nxp), dim3(1024), 0, stream>>>(
            x, Waxw, Waxb, Waaw, Waab, Wyaw, Wyab, out, xp0, xp1, a_state,
            i - 1, i, i >= 1 ? 1 : 0, i < nc ? 1 : 0, i == nc ? 1 : 0,
            T_C, logT);
    }
}